// Round 3
// baseline (855.260 us; speedup 1.0000x reference)
//
#include <hip/hip_runtime.h>

#define T_TOKENS 32768
#define DIM 512
#define FDIM 2048
#define NEXP 8

typedef __attribute__((ext_vector_type(4))) float f32x4;
typedef __attribute__((ext_vector_type(8))) short bf16x8;

__device__ __forceinline__ unsigned short f2bf(float f) {
  unsigned int u = __float_as_uint(f);
  u += 0x7FFFu + ((u >> 16) & 1u);   // round-to-nearest-even
  return (unsigned short)(u >> 16);
}

// Pack W1 [E][D][F] fp32 -> fragment-linear bf16, line-coalesced reads via LDS.
// W1p[((e*128+ft)*16+kci)*512 + l*8 + j] = bf16(W1[e][kci*32+(l>>4)*8+j][ft*16+(l&15)])
__global__ void pack_w1_kernel(const float* __restrict__ W1, unsigned short* __restrict__ W1p) {
  __shared__ float L[512][17];
  const int b = blockIdx.x;          // e*128 + ft
  const int e = b >> 7, ft = b & 127;
  const int t = threadIdx.x;         // 256
  const int c = t & 15, r0 = t >> 4;
  const float* src = W1 + (long)e * 512 * 2048 + ft * 16 + c;
  #pragma unroll
  for (int ch = 0; ch < 32; ch++) {
    int r = ch * 16 + r0;
    L[r][c] = src[(long)r * 2048];
  }
  __syncthreads();
  #pragma unroll
  for (int s = 0; s < 4; s++) {
    int slot = s * 256 + t;
    int kci = slot >> 6, l = slot & 63;
    unsigned short tmp[8];
    #pragma unroll
    for (int j = 0; j < 8; j++)
      tmp[j] = f2bf(L[kci * 32 + (l >> 4) * 8 + j][l & 15]);
    *(ushort4*)(W1p + ((long)b * 16 + kci) * 512 + l * 8)     = *(ushort4*)&tmp[0];
    *(ushort4*)(W1p + ((long)b * 16 + kci) * 512 + l * 8 + 4) = *(ushort4*)&tmp[4];
  }
}

// Pack W2 [E][F][D] fp32 -> fragment-linear bf16, line-coalesced reads via LDS.
// W2p[((e*64+kc2i)*32+dt)*512 + l*8 + j] = bf16(W2[e][kc2i*32+(l>>4)*8+j][dt*16+(l&15)])
__global__ void pack_w2_kernel(const float* __restrict__ W2, unsigned short* __restrict__ W2p) {
  __shared__ float L[512][17];
  const int b = blockIdx.x;          // e*32 + dt
  const int e = b >> 5, dt = b & 31;
  const int t = threadIdx.x;
  const int c = t & 15, r0 = t >> 4;
  for (int ch = 0; ch < 4; ch++) {   // f in chunks of 512
    if (ch) __syncthreads();
    const float* src = W2 + ((long)e * 2048 + ch * 512) * 512 + dt * 16 + c;
    #pragma unroll
    for (int cc = 0; cc < 32; cc++) {
      int r = cc * 16 + r0;
      L[r][c] = src[(long)r * 512];
    }
    __syncthreads();
    #pragma unroll
    for (int s = 0; s < 4; s++) {
      int slot = s * 256 + t;
      int kciL = slot >> 6, l = slot & 63;
      unsigned short tmp[8];
      #pragma unroll
      for (int j = 0; j < 8; j++)
        tmp[j] = f2bf(L[kciL * 32 + (l >> 4) * 8 + j][l & 15]);
      long tt = (long)(e * 64 + ch * 16 + kciL) * 32 + dt;
      *(ushort4*)(W2p + tt * 512 + l * 8)     = *(ushort4*)&tmp[0];
      *(ushort4*)(W2p + tt * 512 + l * 8 + 4) = *(ushort4*)&tmp[4];
    }
  }
}

// one thread per token; per-block LDS histogram -> 8 global atomics per block.
// Emits slots[2t], slots[2t+1] = e*T_TOKENS + s (expert, within-expert slot)
// for each token's two assignments; combine_kernel decodes and compacts.
__global__ void router_kernel(const float* __restrict__ x, const float* __restrict__ Wr,
                              const float* __restrict__ br, int* __restrict__ counts,
                              int* __restrict__ tok_list, float* __restrict__ wt_list,
                              int* __restrict__ slots) {
  __shared__ float WrS[NEXP][DIM];
  __shared__ int lcnt[NEXP];
  __shared__ int lbase[NEXP];
  const int tid = threadIdx.x;   // 256
  for (int i = tid; i < NEXP * DIM; i += 256) {
    int e = i >> 9, d = i & (DIM - 1);
    WrS[e][d] = Wr[d * NEXP + e];
  }
  if (tid < NEXP) lcnt[tid] = 0;
  __syncthreads();

  const int t = blockIdx.x * 256 + tid;
  const float* xr = x + (long)t * DIM;
  float acc[NEXP];
  #pragma unroll
  for (int e = 0; e < NEXP; e++) acc[e] = br[e];
  for (int d = 0; d < DIM; d += 4) {
    const float4 xv = *(const float4*)(xr + d);
    #pragma unroll
    for (int e = 0; e < NEXP; e++)
      acc[e] += xv.x * WrS[e][d] + xv.y * WrS[e][d + 1] +
                xv.z * WrS[e][d + 2] + xv.w * WrS[e][d + 3];
  }
  int e0 = 0; float v0 = acc[0];
  #pragma unroll
  for (int e = 1; e < NEXP; e++) if (acc[e] > v0) { v0 = acc[e]; e0 = e; }
  int e1 = -1; float v1 = -3.4e38f;
  #pragma unroll
  for (int e = 0; e < NEXP; e++) if (e != e0 && acc[e] > v1) { v1 = acc[e]; e1 = e; }
  float w0 = 1.f / (1.f + __expf(v1 - v0));
  float w1 = 1.f - w0;

  int l0 = atomicAdd(&lcnt[e0], 1);
  int l1 = atomicAdd(&lcnt[e1], 1);
  __syncthreads();
  if (tid < NEXP) lbase[tid] = atomicAdd(&counts[tid], lcnt[tid]);
  __syncthreads();
  int s0 = lbase[e0] + l0;
  tok_list[e0 * T_TOKENS + s0] = t; wt_list[e0 * T_TOKENS + s0] = w0;
  int s1 = lbase[e1] + l1;
  tok_list[e1 * T_TOKENS + s1] = t; wt_list[e1 * T_TOKENS + s1] = w1;
  if (slots) {
    slots[2 * t]     = e0 * T_TOKENS + s0;
    slots[2 * t + 1] = e1 * T_TOKENS + s1;
  }
}

#define LD_W1(dst, base)                                        \
  _Pragma("unroll")                                             \
  for (int i = 0; i < 4; i++) {                                 \
    dst[i][0] = *(const bf16x8*)(w1b + (base + i) * 512);       \
    dst[i][1] = *(const bf16x8*)(w1b + (16 + base + i) * 512);  \
  }

#define MF_W1(src, base)                                                          \
  _Pragma("unroll")                                                               \
  for (int i = 0; i < 4; i++) {                                                   \
    int kci = base + i;                                                           \
    int xo = ((kci * 4 + g) ^ xsw) << 3;                                          \
    bf16x8 af0 = *(const bf16x8*)&Xs[xbase0 + xo];                                \
    bf16x8 af1 = *(const bf16x8*)&Xs[xbase0 + 16 * 512 + xo];                     \
    H00 = __builtin_amdgcn_mfma_f32_16x16x32_bf16(af0, src[i][0], H00, 0, 0, 0);  \
    H01 = __builtin_amdgcn_mfma_f32_16x16x32_bf16(af0, src[i][1], H01, 0, 0, 0);  \
    H10 = __builtin_amdgcn_mfma_f32_16x16x32_bf16(af1, src[i][0], H10, 0, 0, 0);  \
    H11 = __builtin_amdgcn_mfma_f32_16x16x32_bf16(af1, src[i][1], H11, 0, 0, 0);  \
  }

#define LD_W2(klbase)                                                             \
  _Pragma("unroll")                                                               \
  for (int kl = klbase; kl < klbase + 2; kl++) {                                  \
    const unsigned short* w2b =                                                   \
        W2p + ((long)((e * 64 + (fc >> 5) + kl) * 32 + wave * 4) * 64 + lane) * 8;\
    _Pragma("unroll")                                                             \
    for (int nt = 0; nt < 4; nt++)                                                \
      w2r[kl][nt] = *(const bf16x8*)(w2b + nt * 512);                             \
  }

// R3 change: 2 blocks/CU (was 1). Round-2 counters showed the classic
// latency/occupancy signature: MfmaUtil 20 + VALUBusy 12 (=> ~68% idle),
// L2 at ~30% of per-XCD ceiling, OccupancyPercent 18.7 -- no pipe near its
// roofline at 1 block/CU (2 waves/SIMD). Single-buffered Hs cuts LDS from
// 96 KB (64 Xs + 2x16 Hs dbuf) to 80 KB (64 + 16) so two 512-thread blocks
// co-reside (2x80 KB = 160 KB LDS exactly, 4 waves/SIMD at VGPR<=128).
// Cost: a 2nd __syncthreads per fc-iter, hidden by the sibling block.
// USE_PARTIAL epilogue (R2, kept): plain coalesced stores to the compact
// partial buffer (row = prefix[e]+slot); combine_kernel sums K=2 rows.
template <bool USE_PARTIAL>
__global__ __launch_bounds__(512, 4) void ffn_kernel(
    const float* __restrict__ x,
    const unsigned short* __restrict__ W1p,
    const unsigned short* __restrict__ W2p,
    const float* __restrict__ b1, const float* __restrict__ b2,
    const int* __restrict__ counts,
    const int* __restrict__ tok_list, const float* __restrict__ wt_list,
    float* __restrict__ partial,
    float* __restrict__ out) {
  __shared__ unsigned short Xs[64 * 512];   // 64 KB
  __shared__ unsigned short Hs[64 * 128];   // 16 KB (single-buffered)

  const int e = blockIdx.x & 7;        // expert -> XCD pinning
  const int tile = blockIdx.x >> 3;
  const int cnt = counts[e];
  const int m0 = tile * 64;
  if (m0 >= cnt) return;
  const int rows = min(64, cnt - m0);

  // compact base row for this expert in the partial buffer
  int pbase = 0;
  if (USE_PARTIAL) {
    #pragma unroll
    for (int i = 0; i < NEXP; i++) pbase += (i < e) ? counts[i] : 0;
  }

  const int tid = threadIdx.x;
  const int wave = tid >> 6, lane = tid & 63;
  const int g = lane >> 4, ln = lane & 15;
  const int mw = wave >> 2, nw = wave & 3;   // GEMM1 wave grid: 2(m) x 4(n)

  // stage gathered X tile (fp32 -> bf16), XOR-swizzled
  #pragma unroll 4
  for (int c = tid; c < 64 * 128; c += 512) {
    int r = c >> 7, q = c & 127;
    ushort4 bv = {0, 0, 0, 0};
    if (r < rows) {
      int tk = tok_list[e * T_TOKENS + m0 + r];
      const float4 v = *(const float4*)(x + (long)tk * DIM + q * 4);
      bv.x = f2bf(v.x); bv.y = f2bf(v.y); bv.z = f2bf(v.z); bv.w = f2bf(v.w);
    }
    int addr = r * 512 + ((((q >> 1) ^ (r & 7)) << 3) | ((q & 1) << 2));
    *(ushort4*)&Xs[addr] = bv;
  }
  __syncthreads();

  const f32x4 zero4 = {0.f, 0.f, 0.f, 0.f};
  f32x4 Yacc[4][4];
  #pragma unroll
  for (int a = 0; a < 4; a++)
    #pragma unroll
    for (int b = 0; b < 4; b++) Yacc[a][b] = zero4;

  const int xsw = ln & 7;
  const int xbase0 = (mw * 32 + ln) * 512;

  for (int fc = 0; fc < FDIM; fc += 128) {
    unsigned short* Hp = &Hs[0];
    f32x4 H00 = zero4, H01 = zero4, H10 = zero4, H11 = zero4;
    const unsigned short* w1b =
        W1p + ((long)(e * 128 + (fc >> 4) + nw * 2) * 16) * 512 + lane * 8;

    bf16x8 wA[4][2], wB[4][2], w2r[4][4];
    // software-pipelined GEMM1: load batch i+1 while MFMAing batch i
    LD_W1(wA, 0);
    LD_W1(wB, 4);
    MF_W1(wA, 0);
    LD_W1(wA, 8);
    MF_W1(wB, 4);
    LD_W1(wB, 12);
    MF_W1(wA, 8);
    LD_W2(0);          // prefetch GEMM2 kl 0,1 during GEMM1 tail
    MF_W1(wB, 12);

    // barrier A: previous iter's GEMM2 reads of Hs must drain before rewrite.
    // (GEMM2(i-1) and GEMM1(i) both sit between barrier B(i-1) and here.)
    __syncthreads();

    // bias + relu -> Hs (C-layout: col=lane&15, row=(lane>>4)*4+i)
    {
      float b1v0 = b1[e * FDIM + fc + nw * 32 + ln];
      float b1v1 = b1[e * FDIM + fc + nw * 32 + 16 + ln];
      #pragma unroll
      for (int mi = 0; mi < 2; mi++) {
        #pragma unroll
        for (int ni = 0; ni < 2; ni++) {
          const f32x4& hv = mi ? (ni ? H11 : H10) : (ni ? H01 : H00);
          float bv = ni ? b1v1 : b1v0;
          int fl = nw * 32 + ni * 16 + ln;
          #pragma unroll
          for (int i = 0; i < 4; i++) {
            int m = mw * 32 + mi * 16 + g * 4 + i;
            int addr = m * 128 + ((((fl >> 3) ^ (m & 7)) << 3) | (fl & 7));
            Hp[addr] = f2bf(fmaxf(hv[i] + bv, 0.f));
          }
        }
      }
    }
    __syncthreads();   // barrier B: Hs writes visible before GEMM2 reads

    LD_W2(2);          // prefetch kl 2,3 under kl 0,1 MFMAs

    #pragma unroll
    for (int kl = 0; kl < 4; kl++) {
      bf16x8 ha[4];
      #pragma unroll
      for (int mt = 0; mt < 4; mt++) {
        int m = mt * 16 + ln;
        ha[mt] = *(const bf16x8*)&Hp[m * 128 + ((((kl * 4 + g) ^ (m & 7)) << 3))];
      }
      #pragma unroll
      for (int nt = 0; nt < 4; nt++)
        #pragma unroll
        for (int mt = 0; mt < 4; mt++)
          Yacc[mt][nt] = __builtin_amdgcn_mfma_f32_16x16x32_bf16(ha[mt], w2r[kl][nt], Yacc[mt][nt], 0, 0, 0);
    }
  }

  // epilogue: (Y + b2) * token_weight
  #pragma unroll
  for (int mt = 0; mt < 4; mt++) {
    #pragma unroll
    for (int i = 0; i < 4; i++) {
      int m = mt * 16 + g * 4 + i;
      if (m < rows) {
        float w = wt_list[e * T_TOKENS + m0 + m];
        if (USE_PARTIAL) {
          // coalesced non-atomic store of this assignment's weighted row slice
          float* dst = partial + ((long)(pbase + m0 + m)) * DIM;
          #pragma unroll
          for (int nt = 0; nt < 4; nt++) {
            int d = (wave * 4 + nt) * 16 + ln;
            dst[d] = (Yacc[mt][nt][i] + b2[e * DIM + d]) * w;
          }
        } else {
          int tk = tok_list[e * T_TOKENS + m0 + m];
          #pragma unroll
          for (int nt = 0; nt < 4; nt++) {
            int d = (wave * 4 + nt) * 16 + ln;
            float v = (Yacc[mt][nt][i] + b2[e * DIM + d]) * w;
            atomicAdd(out + (long)tk * DIM + d, v);
          }
        }
      }
    }
  }
}

// out[t] = partial[row(slots[2t])] + partial[row(slots[2t+1])] ; pure
// streaming, no RMW. row(slot) = prefix[e] + s with slot = e*T_TOKENS + s.
// 256 threads = 2 tokens/block, float4 per thread.
__global__ __launch_bounds__(256) void combine_kernel(
    const float* __restrict__ partial, const int* __restrict__ slots,
    const int* __restrict__ counts, float* __restrict__ out) {
  __shared__ int pre[NEXP];
  if (threadIdx.x == 0) {
    int a = 0;
    #pragma unroll
    for (int i = 0; i < NEXP; i++) { pre[i] = a; a += counts[i]; }
  }
  __syncthreads();
  const int tid = threadIdx.x;
  const int tk = blockIdx.x * 2 + (tid >> 7);
  const int q = (tid & 127) << 2;
  const int2 sp = *(const int2*)(slots + 2 * tk);
  const long r0 = pre[sp.x >> 15] + (sp.x & (T_TOKENS - 1));
  const long r1 = pre[sp.y >> 15] + (sp.y & (T_TOKENS - 1));
  const float4 a = *(const float4*)(partial + r0 * DIM + q);
  const float4 b = *(const float4*)(partial + r1 * DIM + q);
  float4 r;
  r.x = a.x + b.x; r.y = a.y + b.y; r.z = a.z + b.z; r.w = a.w + b.w;
  *(float4*)(out + (long)tk * DIM + q) = r;
}

extern "C" void kernel_launch(void* const* d_in, const int* in_sizes, int n_in,
                              void* d_out, int out_size, void* d_ws, size_t ws_size,
                              hipStream_t stream) {
  (void)in_sizes; (void)n_in; (void)out_size;
  const float* x  = (const float*)d_in[0];
  const float* Wr = (const float*)d_in[1];
  const float* br = (const float*)d_in[2];
  const float* W1 = (const float*)d_in[3];
  const float* b1 = (const float*)d_in[4];
  const float* W2 = (const float*)d_in[5];
  const float* b2 = (const float*)d_in[6];
  float* out = (float*)d_out;

  char* ws = (char*)d_ws;
  // layout (bytes):
  //   counts   @ 0          (1,024)
  //   tok_list @ 1,024      (1,048,576)
  //   wt_list  @ 1,049,600  (1,048,576)
  //   slots    @ 2,098,176  (262,144)
  //   W1p      @ 2,360,320  (16,777,216)
  //   W2p      @ 19,137,536 (16,777,216)
  //   partial  @ 35,914,752 (134,217,728 = 2*T rows x 512 f32) -> end 170,132,480
  int*            counts   = (int*)(ws);
  int*            tok_list = (int*)(ws + 1024);
  float*          wt_list  = (float*)(ws + 1049600);
  int*            slots    = (int*)(ws + 2098176);
  unsigned short* W1p      = (unsigned short*)(ws + 2360320);
  unsigned short* W2p      = (unsigned short*)(ws + 19137536);
  float*          partial  = (float*)(ws + 35914752);
  const size_t need_partial = 35914752ull + (size_t)T_TOKENS * 2 * DIM * sizeof(float);
  const bool use_partial = ws_size >= need_partial;

  hipMemsetAsync(counts, 0, 1024, stream);
  pack_w1_kernel<<<NEXP * 128, 256, 0, stream>>>(W1, W1p);
  pack_w2_kernel<<<NEXP * 32, 256, 0, stream>>>(W2, W2p);

  if (use_partial) {
    router_kernel<<<T_TOKENS / 256, 256, 0, stream>>>(x, Wr, br, counts, tok_list, wt_list, slots);
    ffn_kernel<true><<<T_TOKENS / 64 * NEXP, 512, 0, stream>>>(
        x, W1p, W2p, b1, b2, counts, tok_list, wt_list, partial, out);
    combine_kernel<<<T_TOKENS / 2, 256, 0, stream>>>(partial, slots, counts, out);
  } else {
    // fallback: original atomic-accumulate path
    hipMemsetAsync(out, 0, (size_t)T_TOKENS * DIM * sizeof(float), stream);
    router_kernel<<<T_TOKENS / 256, 256, 0, stream>>>(x, Wr, br, counts, tok_list, wt_list, nullptr);
    ffn_kernel<false><<<T_TOKENS / 64 * NEXP, 512, 0, stream>>>(
        x, W1p, W2p, b1, b2, counts, tok_list, wt_list, nullptr, out);
  }
}

// Round 4
// 812.245 us; speedup vs baseline: 1.0530x; 1.0530x over previous
//
#include <hip/hip_runtime.h>

#define T_TOKENS 32768
#define DIM 512
#define FDIM 2048
#define NEXP 8

typedef __attribute__((ext_vector_type(4))) float f32x4;
typedef __attribute__((ext_vector_type(8))) short bf16x8;

__device__ __forceinline__ unsigned short f2bf(float f) {
  unsigned int u = __float_as_uint(f);
  u += 0x7FFFu + ((u >> 16) & 1u);   // round-to-nearest-even
  return (unsigned short)(u >> 16);
}

// Pack W1 [E][D][F] fp32 -> fragment-linear bf16, line-coalesced reads via LDS.
// W1p[((e*128+ft)*16+kci)*512 + l*8 + j] = bf16(W1[e][kci*32+(l>>4)*8+j][ft*16+(l&15)])
__global__ void pack_w1_kernel(const float* __restrict__ W1, unsigned short* __restrict__ W1p) {
  __shared__ float L[512][17];
  const int b = blockIdx.x;          // e*128 + ft
  const int e = b >> 7, ft = b & 127;
  const int t = threadIdx.x;         // 256
  const int c = t & 15, r0 = t >> 4;
  const float* src = W1 + (long)e * 512 * 2048 + ft * 16 + c;
  #pragma unroll
  for (int ch = 0; ch < 32; ch++) {
    int r = ch * 16 + r0;
    L[r][c] = src[(long)r * 2048];
  }
  __syncthreads();
  #pragma unroll
  for (int s = 0; s < 4; s++) {
    int slot = s * 256 + t;
    int kci = slot >> 6, l = slot & 63;
    unsigned short tmp[8];
    #pragma unroll
    for (int j = 0; j < 8; j++)
      tmp[j] = f2bf(L[kci * 32 + (l >> 4) * 8 + j][l & 15]);
    *(ushort4*)(W1p + ((long)b * 16 + kci) * 512 + l * 8)     = *(ushort4*)&tmp[0];
    *(ushort4*)(W1p + ((long)b * 16 + kci) * 512 + l * 8 + 4) = *(ushort4*)&tmp[4];
  }
}

// Pack W2 [E][F][D] fp32 -> fragment-linear bf16, line-coalesced reads via LDS.
// W2p[((e*64+kc2i)*32+dt)*512 + l*8 + j] = bf16(W2[e][kc2i*32+(l>>4)*8+j][dt*16+(l&15)])
__global__ void pack_w2_kernel(const float* __restrict__ W2, unsigned short* __restrict__ W2p) {
  __shared__ float L[512][17];
  const int b = blockIdx.x;          // e*32 + dt
  const int e = b >> 5, dt = b & 31;
  const int t = threadIdx.x;
  const int c = t & 15, r0 = t >> 4;
  for (int ch = 0; ch < 4; ch++) {   // f in chunks of 512
    if (ch) __syncthreads();
    const float* src = W2 + ((long)e * 2048 + ch * 512) * 512 + dt * 16 + c;
    #pragma unroll
    for (int cc = 0; cc < 32; cc++) {
      int r = cc * 16 + r0;
      L[r][c] = src[(long)r * 512];
    }
    __syncthreads();
    #pragma unroll
    for (int s = 0; s < 4; s++) {
      int slot = s * 256 + t;
      int kciL = slot >> 6, l = slot & 63;
      unsigned short tmp[8];
      #pragma unroll
      for (int j = 0; j < 8; j++)
        tmp[j] = f2bf(L[kciL * 32 + (l >> 4) * 8 + j][l & 15]);
      long tt = (long)(e * 64 + ch * 16 + kciL) * 32 + dt;
      *(ushort4*)(W2p + tt * 512 + l * 8)     = *(ushort4*)&tmp[0];
      *(ushort4*)(W2p + tt * 512 + l * 8 + 4) = *(ushort4*)&tmp[4];
    }
  }
}

// one thread per token; per-block LDS histogram -> 8 global atomics per block.
// Emits slots[2t], slots[2t+1] = e*T_TOKENS + s (expert, within-expert slot)
// for each token's two assignments; combine_kernel decodes and compacts.
__global__ void router_kernel(const float* __restrict__ x, const float* __restrict__ Wr,
                              const float* __restrict__ br, int* __restrict__ counts,
                              int* __restrict__ tok_list, float* __restrict__ wt_list,
                              int* __restrict__ slots) {
  __shared__ float WrS[NEXP][DIM];
  __shared__ int lcnt[NEXP];
  __shared__ int lbase[NEXP];
  const int tid = threadIdx.x;   // 256
  for (int i = tid; i < NEXP * DIM; i += 256) {
    int e = i >> 9, d = i & (DIM - 1);
    WrS[e][d] = Wr[d * NEXP + e];
  }
  if (tid < NEXP) lcnt[tid] = 0;
  __syncthreads();

  const int t = blockIdx.x * 256 + tid;
  const float* xr = x + (long)t * DIM;
  float acc[NEXP];
  #pragma unroll
  for (int e = 0; e < NEXP; e++) acc[e] = br[e];
  for (int d = 0; d < DIM; d += 4) {
    const float4 xv = *(const float4*)(xr + d);
    #pragma unroll
    for (int e = 0; e < NEXP; e++)
      acc[e] += xv.x * WrS[e][d] + xv.y * WrS[e][d + 1] +
                xv.z * WrS[e][d + 2] + xv.w * WrS[e][d + 3];
  }
  int e0 = 0; float v0 = acc[0];
  #pragma unroll
  for (int e = 1; e < NEXP; e++) if (acc[e] > v0) { v0 = acc[e]; e0 = e; }
  int e1 = -1; float v1 = -3.4e38f;
  #pragma unroll
  for (int e = 0; e < NEXP; e++) if (e != e0 && acc[e] > v1) { v1 = acc[e]; e1 = e; }
  float w0 = 1.f / (1.f + __expf(v1 - v0));
  float w1 = 1.f - w0;

  int l0 = atomicAdd(&lcnt[e0], 1);
  int l1 = atomicAdd(&lcnt[e1], 1);
  __syncthreads();
  if (tid < NEXP) lbase[tid] = atomicAdd(&counts[tid], lcnt[tid]);
  __syncthreads();
  int s0 = lbase[e0] + l0;
  tok_list[e0 * T_TOKENS + s0] = t; wt_list[e0 * T_TOKENS + s0] = w0;
  int s1 = lbase[e1] + l1;
  tok_list[e1 * T_TOKENS + s1] = t; wt_list[e1 * T_TOKENS + s1] = w1;
  if (slots) {
    slots[2 * t]     = e0 * T_TOKENS + s0;
    slots[2 * t + 1] = e1 * T_TOKENS + s1;
  }
}

#define LD_W1(dst, base)                                        \
  _Pragma("unroll")                                             \
  for (int i = 0; i < 4; i++) {                                 \
    dst[i][0] = *(const bf16x8*)(w1b + (base + i) * 512);       \
    dst[i][1] = *(const bf16x8*)(w1b + (16 + base + i) * 512);  \
  }

#define MF_W1(src, base)                                                          \
  _Pragma("unroll")                                                               \
  for (int i = 0; i < 4; i++) {                                                   \
    int kci = base + i;                                                           \
    int xo = ((kci * 4 + g) ^ xsw) << 3;                                          \
    bf16x8 af0 = *(const bf16x8*)&Xs[xbase0 + xo];                                \
    bf16x8 af1 = *(const bf16x8*)&Xs[xbase0 + 16 * 512 + xo];                     \
    H00 = __builtin_amdgcn_mfma_f32_16x16x32_bf16(af0, src[i][0], H00, 0, 0, 0);  \
    H01 = __builtin_amdgcn_mfma_f32_16x16x32_bf16(af0, src[i][1], H01, 0, 0, 0);  \
    H10 = __builtin_amdgcn_mfma_f32_16x16x32_bf16(af1, src[i][0], H10, 0, 0, 0);  \
    H11 = __builtin_amdgcn_mfma_f32_16x16x32_bf16(af1, src[i][1], H11, 0, 0, 0);  \
  }

#define LD_W2(klbase)                                                             \
  _Pragma("unroll")                                                               \
  for (int kl = klbase; kl < klbase + 2; kl++) {                                  \
    const unsigned short* w2b =                                                   \
        W2p + ((long)((e * 64 + (fc >> 5) + kl) * 32 + wave * 4) * 64 + lane) * 8;\
    _Pragma("unroll")                                                             \
    for (int nt = 0; nt < 4; nt++)                                                \
      w2r[kl][nt] = *(const bf16x8*)(w2b + nt * 512);                             \
  }

// R4: revert R3's occupancy experiment (it squeezed VGPR 112->64 and
// quadrupled FETCH via lost register pipelining + L2 thrash). Back to
// 1 block/CU (LDS 96 KB: Xs 64 + Hs dbuf 2x16), launch_bounds(512,2),
// and instead attack latency with DEEPER PER-WAVE PREFETCH:
//  - cross-iteration prefetch: next iter's W1 kci 0..7 (wA,wB) issued
//    during current iter's tail -> ~full-iter (800+ cyc) coverage;
//  - in-iter: kci 8..11 (wC) at iter top covered by 2 MFMA batches;
//    kci 12..15 reloads wB covered by MF(wC)+LD_W2+LD(wA_next).
// Every vmcnt wait now has >=160 cyc of issued work in front of it
// (was ~50 for the first batch of every iter).
template <bool USE_PARTIAL>
__global__ __launch_bounds__(512, 2) void ffn_kernel(
    const float* __restrict__ x,
    const unsigned short* __restrict__ W1p,
    const unsigned short* __restrict__ W2p,
    const float* __restrict__ b1, const float* __restrict__ b2,
    const int* __restrict__ counts,
    const int* __restrict__ tok_list, const float* __restrict__ wt_list,
    float* __restrict__ partial,
    float* __restrict__ out) {
  __shared__ unsigned short Xs[64 * 512];   // 64 KB
  __shared__ unsigned short Hs[2][64 * 128];// 32 KB double-buffered

  const int e = blockIdx.x & 7;        // expert -> XCD pinning
  const int tile = blockIdx.x >> 3;
  const int cnt = counts[e];
  const int m0 = tile * 64;
  if (m0 >= cnt) return;
  const int rows = min(64, cnt - m0);

  // compact base row for this expert in the partial buffer
  int pbase = 0;
  if (USE_PARTIAL) {
    #pragma unroll
    for (int i = 0; i < NEXP; i++) pbase += (i < e) ? counts[i] : 0;
  }

  const int tid = threadIdx.x;
  const int wave = tid >> 6, lane = tid & 63;
  const int g = lane >> 4, ln = lane & 15;
  const int mw = wave >> 2, nw = wave & 3;   // GEMM1 wave grid: 2(m) x 4(n)

  // stage gathered X tile (fp32 -> bf16), XOR-swizzled
  #pragma unroll 4
  for (int c = tid; c < 64 * 128; c += 512) {
    int r = c >> 7, q = c & 127;
    ushort4 bv = {0, 0, 0, 0};
    if (r < rows) {
      int tk = tok_list[e * T_TOKENS + m0 + r];
      const float4 v = *(const float4*)(x + (long)tk * DIM + q * 4);
      bv.x = f2bf(v.x); bv.y = f2bf(v.y); bv.z = f2bf(v.z); bv.w = f2bf(v.w);
    }
    int addr = r * 512 + ((((q >> 1) ^ (r & 7)) << 3) | ((q & 1) << 2));
    *(ushort4*)&Xs[addr] = bv;
  }
  __syncthreads();

  const f32x4 zero4 = {0.f, 0.f, 0.f, 0.f};
  f32x4 Yacc[4][4];
  #pragma unroll
  for (int a = 0; a < 4; a++)
    #pragma unroll
    for (int b = 0; b < 4; b++) Yacc[a][b] = zero4;

  const int xsw = ln & 7;
  const int xbase0 = (mw * 32 + ln) * 512;

  const unsigned short* const w1b_first =
      W1p + ((long)(e * 128 + nw * 2) * 16) * 512 + lane * 8;
  const unsigned short* w1b = w1b_first;

  bf16x8 wA[4][2], wB[4][2], wC[4][2], w2r[4][4];
  // prologue: prefetch iter-0 kci 0..7 (one full-latency wait per block, amortized)
  LD_W1(wA, 0);
  LD_W1(wB, 4);

  for (int fc = 0; fc < FDIM; fc += 128) {
    unsigned short* Hp = &Hs[(fc >> 7) & 1][0];
    f32x4 H00 = zero4, H01 = zero4, H10 = zero4, H11 = zero4;

    LD_W1(wC, 8);        // in-iter batch: kci 8..11
    MF_W1(wA, 0);        // cross-iter prefetched -> wait fully covered
    MF_W1(wB, 4);        // cross-iter prefetched
    LD_W1(wB, 12);       // wB free -> reload with kci 12..15
    MF_W1(wC, 8);        // covered by MF(wA)+MF(wB) ~160 cyc
    LD_W2(0);            // GEMM2 kl 0,1 prefetch (consumed after barrier)
    // advance W1 base for next fc-iter (last iter: re-point at iter-0 data;
    // those prefetch loads are valid reads whose values are never used)
    w1b = (fc + 128 < FDIM) ? (w1b + 8 * 16 * 512) : w1b_first;
    LD_W1(wA, 0);        // next-iter kci 0..3 (cross-iter prefetch)
    MF_W1(wB, 12);       // covered by MF(wC)+LD_W2+LD(wA_next) ~180 cyc
    LD_W1(wB, 4);        // next-iter kci 4..7 (cross-iter prefetch)

    // bias + relu -> Hs[p] (C-layout: col=lane&15, row=(lane>>4)*4+i)
    {
      float b1v0 = b1[e * FDIM + fc + nw * 32 + ln];
      float b1v1 = b1[e * FDIM + fc + nw * 32 + 16 + ln];
      #pragma unroll
      for (int mi = 0; mi < 2; mi++) {
        #pragma unroll
        for (int ni = 0; ni < 2; ni++) {
          const f32x4& hv = mi ? (ni ? H11 : H10) : (ni ? H01 : H00);
          float bv = ni ? b1v1 : b1v0;
          int fl = nw * 32 + ni * 16 + ln;
          #pragma unroll
          for (int i = 0; i < 4; i++) {
            int m = mw * 32 + mi * 16 + g * 4 + i;
            int addr = m * 128 + ((((fl >> 3) ^ (m & 7)) << 3) | (fl & 7));
            Hp[addr] = f2bf(fmaxf(hv[i] + bv, 0.f));
          }
        }
      }
    }
    __syncthreads();   // single barrier per fc-iter (Hs double-buffered)

    LD_W2(2);          // prefetch kl 2,3 under kl 0,1 MFMAs

    #pragma unroll
    for (int kl = 0; kl < 4; kl++) {
      bf16x8 ha[4];
      #pragma unroll
      for (int mt = 0; mt < 4; mt++) {
        int m = mt * 16 + ln;
        ha[mt] = *(const bf16x8*)&Hp[m * 128 + ((((kl * 4 + g) ^ (m & 7)) << 3))];
      }
      #pragma unroll
      for (int nt = 0; nt < 4; nt++)
        #pragma unroll
        for (int mt = 0; mt < 4; mt++)
          Yacc[mt][nt] = __builtin_amdgcn_mfma_f32_16x16x32_bf16(ha[mt], w2r[kl][nt], Yacc[mt][nt], 0, 0, 0);
    }
  }

  // epilogue: (Y + b2) * token_weight
  #pragma unroll
  for (int mt = 0; mt < 4; mt++) {
    #pragma unroll
    for (int i = 0; i < 4; i++) {
      int m = mt * 16 + g * 4 + i;
      if (m < rows) {
        float w = wt_list[e * T_TOKENS + m0 + m];
        if (USE_PARTIAL) {
          // coalesced non-atomic store of this assignment's weighted row slice
          float* dst = partial + ((long)(pbase + m0 + m)) * DIM;
          #pragma unroll
          for (int nt = 0; nt < 4; nt++) {
            int d = (wave * 4 + nt) * 16 + ln;
            dst[d] = (Yacc[mt][nt][i] + b2[e * DIM + d]) * w;
          }
        } else {
          int tk = tok_list[e * T_TOKENS + m0 + m];
          #pragma unroll
          for (int nt = 0; nt < 4; nt++) {
            int d = (wave * 4 + nt) * 16 + ln;
            float v = (Yacc[mt][nt][i] + b2[e * DIM + d]) * w;
            atomicAdd(out + (long)tk * DIM + d, v);
          }
        }
      }
    }
  }
}

// out[t] = partial[row(slots[2t])] + partial[row(slots[2t+1])] ; pure
// streaming, no RMW. row(slot) = prefix[e] + s with slot = e*T_TOKENS + s.
// 256 threads = 2 tokens/block, float4 per thread.
__global__ __launch_bounds__(256) void combine_kernel(
    const float* __restrict__ partial, const int* __restrict__ slots,
    const int* __restrict__ counts, float* __restrict__ out) {
  __shared__ int pre[NEXP];
  if (threadIdx.x == 0) {
    int a = 0;
    #pragma unroll
    for (int i = 0; i < NEXP; i++) { pre[i] = a; a += counts[i]; }
  }
  __syncthreads();
  const int tid = threadIdx.x;
  const int tk = blockIdx.x * 2 + (tid >> 7);
  const int q = (tid & 127) << 2;
  const int2 sp = *(const int2*)(slots + 2 * tk);
  const long r0 = pre[sp.x >> 15] + (sp.x & (T_TOKENS - 1));
  const long r1 = pre[sp.y >> 15] + (sp.y & (T_TOKENS - 1));
  const float4 a = *(const float4*)(partial + r0 * DIM + q);
  const float4 b = *(const float4*)(partial + r1 * DIM + q);
  float4 r;
  r.x = a.x + b.x; r.y = a.y + b.y; r.z = a.z + b.z; r.w = a.w + b.w;
  *(float4*)(out + (long)tk * DIM + q) = r;
}

extern "C" void kernel_launch(void* const* d_in, const int* in_sizes, int n_in,
                              void* d_out, int out_size, void* d_ws, size_t ws_size,
                              hipStream_t stream) {
  (void)in_sizes; (void)n_in; (void)out_size;
  const float* x  = (const float*)d_in[0];
  const float* Wr = (const float*)d_in[1];
  const float* br = (const float*)d_in[2];
  const float* W1 = (const float*)d_in[3];
  const float* b1 = (const float*)d_in[4];
  const float* W2 = (const float*)d_in[5];
  const float* b2 = (const float*)d_in[6];
  float* out = (float*)d_out;

  char* ws = (char*)d_ws;
  // layout (bytes):
  //   counts   @ 0          (1,024)
  //   tok_list @ 1,024      (1,048,576)
  //   wt_list  @ 1,049,600  (1,048,576)
  //   slots    @ 2,098,176  (262,144)
  //   W1p      @ 2,360,320  (16,777,216)
  //   W2p      @ 19,137,536 (16,777,216)
  //   partial  @ 35,914,752 (134,217,728 = 2*T rows x 512 f32) -> end 170,132,480
  int*            counts   = (int*)(ws);
  int*            tok_list = (int*)(ws + 1024);
  float*          wt_list  = (float*)(ws + 1049600);
  int*            slots    = (int*)(ws + 2098176);
  unsigned short* W1p      = (unsigned short*)(ws + 2360320);
  unsigned short* W2p      = (unsigned short*)(ws + 19137536);
  float*          partial  = (float*)(ws + 35914752);
  const size_t need_partial = 35914752ull + (size_t)T_TOKENS * 2 * DIM * sizeof(float);
  const bool use_partial = ws_size >= need_partial;

  hipMemsetAsync(counts, 0, 1024, stream);
  pack_w1_kernel<<<NEXP * 128, 256, 0, stream>>>(W1, W1p);
  pack_w2_kernel<<<NEXP * 32, 256, 0, stream>>>(W2, W2p);

  if (use_partial) {
    router_kernel<<<T_TOKENS / 256, 256, 0, stream>>>(x, Wr, br, counts, tok_list, wt_list, slots);
    ffn_kernel<true><<<T_TOKENS / 64 * NEXP, 512, 0, stream>>>(
        x, W1p, W2p, b1, b2, counts, tok_list, wt_list, partial, out);
    combine_kernel<<<T_TOKENS / 2, 256, 0, stream>>>(partial, slots, counts, out);
  } else {
    // fallback: original atomic-accumulate path
    hipMemsetAsync(out, 0, (size_t)T_TOKENS * DIM * sizeof(float), stream);
    router_kernel<<<T_TOKENS / 256, 256, 0, stream>>>(x, Wr, br, counts, tok_list, wt_list, nullptr);
    ffn_kernel<false><<<T_TOKENS / 64 * NEXP, 512, 0, stream>>>(
        x, W1p, W2p, b1, b2, counts, tok_list, wt_list, nullptr, out);
  }
}

// Round 6
// 705.644 us; speedup vs baseline: 1.2120x; 1.1511x over previous
//
#include <hip/hip_runtime.h>

#define T_TOKENS 32768
#define DIM 512
#define FDIM 2048
#define NEXP 8

typedef __attribute__((ext_vector_type(4))) float f32x4;
typedef __attribute__((ext_vector_type(8))) short bf16x8;

__device__ __forceinline__ unsigned short f2bf(float f) {
  unsigned int u = __float_as_uint(f);
  u += 0x7FFFu + ((u >> 16) & 1u);   // round-to-nearest-even
  return (unsigned short)(u >> 16);
}

// Barrier that does NOT drain vmcnt: hipcc's __syncthreads emits
// "s_waitcnt vmcnt(0) lgkmcnt(0); s_barrier", which kills every in-flight
// register prefetch (R2-R4 all ~600us regardless of prefetch depth -- the
// barrier reset vmcnt each iter). Cross-wave visibility here only needs the
// LDS writes (lgkmcnt); vmem loads target per-wave registers and may stay
// outstanding across the barrier (T4, m218: +38-73%).
#define LGKM_BARRIER()                                        \
  do {                                                        \
    asm volatile("s_waitcnt lgkmcnt(0)" ::: "memory");        \
    __builtin_amdgcn_s_barrier();                             \
  } while (0)

// Pack W1 [E][D][F] fp32 -> fragment-linear bf16, line-coalesced reads via LDS.
// W1p[((e*128+ft)*16+kci)*512 + l*8 + j] = bf16(W1[e][kci*32+(l>>4)*8+j][ft*16+(l&15)])
__global__ void pack_w1_kernel(const float* __restrict__ W1, unsigned short* __restrict__ W1p) {
  __shared__ float L[512][17];
  const int b = blockIdx.x;          // e*128 + ft
  const int e = b >> 7, ft = b & 127;
  const int t = threadIdx.x;         // 256
  const int c = t & 15, r0 = t >> 4;
  const float* src = W1 + (long)e * 512 * 2048 + ft * 16 + c;
  #pragma unroll
  for (int ch = 0; ch < 32; ch++) {
    int r = ch * 16 + r0;
    L[r][c] = src[(long)r * 2048];
  }
  __syncthreads();
  #pragma unroll
  for (int s = 0; s < 4; s++) {
    int slot = s * 256 + t;
    int kci = slot >> 6, l = slot & 63;
    unsigned short tmp[8];
    #pragma unroll
    for (int j = 0; j < 8; j++)
      tmp[j] = f2bf(L[kci * 32 + (l >> 4) * 8 + j][l & 15]);
    *(ushort4*)(W1p + ((long)b * 16 + kci) * 512 + l * 8)     = *(ushort4*)&tmp[0];
    *(ushort4*)(W1p + ((long)b * 16 + kci) * 512 + l * 8 + 4) = *(ushort4*)&tmp[4];
  }
}

// Pack W2 [E][F][D] fp32 -> fragment-linear bf16, line-coalesced reads via LDS.
// W2p[((e*64+kc2i)*32+dt)*512 + l*8 + j] = bf16(W2[e][kc2i*32+(l>>4)*8+j][dt*16+(l&15)])
__global__ void pack_w2_kernel(const float* __restrict__ W2, unsigned short* __restrict__ W2p) {
  __shared__ float L[512][17];
  const int b = blockIdx.x;          // e*32 + dt
  const int e = b >> 5, dt = b & 31;
  const int t = threadIdx.x;
  const int c = t & 15, r0 = t >> 4;
  for (int ch = 0; ch < 4; ch++) {   // f in chunks of 512
    if (ch) __syncthreads();
    const float* src = W2 + ((long)e * 2048 + ch * 512) * 512 + dt * 16 + c;
    #pragma unroll
    for (int cc = 0; cc < 32; cc++) {
      int r = cc * 16 + r0;
      L[r][c] = src[(long)r * 512];
    }
    __syncthreads();
    #pragma unroll
    for (int s = 0; s < 4; s++) {
      int slot = s * 256 + t;
      int kciL = slot >> 6, l = slot & 63;
      unsigned short tmp[8];
      #pragma unroll
      for (int j = 0; j < 8; j++)
        tmp[j] = f2bf(L[kciL * 32 + (l >> 4) * 8 + j][l & 15]);
      long tt = (long)(e * 64 + ch * 16 + kciL) * 32 + dt;
      *(ushort4*)(W2p + tt * 512 + l * 8)     = *(ushort4*)&tmp[0];
      *(ushort4*)(W2p + tt * 512 + l * 8 + 4) = *(ushort4*)&tmp[4];
    }
  }
}

// one thread per token; per-block LDS histogram -> 8 global atomics per block.
// Emits slots[2t], slots[2t+1] = e*T_TOKENS + s (expert, within-expert slot)
// for each token's two assignments; combine_kernel decodes and compacts.
__global__ void router_kernel(const float* __restrict__ x, const float* __restrict__ Wr,
                              const float* __restrict__ br, int* __restrict__ counts,
                              int* __restrict__ tok_list, float* __restrict__ wt_list,
                              int* __restrict__ slots) {
  __shared__ float WrS[NEXP][DIM];
  __shared__ int lcnt[NEXP];
  __shared__ int lbase[NEXP];
  const int tid = threadIdx.x;   // 256
  for (int i = tid; i < NEXP * DIM; i += 256) {
    int e = i >> 9, d = i & (DIM - 1);
    WrS[e][d] = Wr[d * NEXP + e];
  }
  if (tid < NEXP) lcnt[tid] = 0;
  __syncthreads();

  const int t = blockIdx.x * 256 + tid;
  const float* xr = x + (long)t * DIM;
  float acc[NEXP];
  #pragma unroll
  for (int e = 0; e < NEXP; e++) acc[e] = br[e];
  for (int d = 0; d < DIM; d += 4) {
    const float4 xv = *(const float4*)(xr + d);
    #pragma unroll
    for (int e = 0; e < NEXP; e++)
      acc[e] += xv.x * WrS[e][d] + xv.y * WrS[e][d + 1] +
                xv.z * WrS[e][d + 2] + xv.w * WrS[e][d + 3];
  }
  int e0 = 0; float v0 = acc[0];
  #pragma unroll
  for (int e = 1; e < NEXP; e++) if (acc[e] > v0) { v0 = acc[e]; e0 = e; }
  int e1 = -1; float v1 = -3.4e38f;
  #pragma unroll
  for (int e = 0; e < NEXP; e++) if (e != e0 && acc[e] > v1) { v1 = acc[e]; e1 = e; }
  float w0 = 1.f / (1.f + __expf(v1 - v0));
  float w1 = 1.f - w0;

  int l0 = atomicAdd(&lcnt[e0], 1);
  int l1 = atomicAdd(&lcnt[e1], 1);
  __syncthreads();
  if (tid < NEXP) lbase[tid] = atomicAdd(&counts[tid], lcnt[tid]);
  __syncthreads();
  int s0 = lbase[e0] + l0;
  tok_list[e0 * T_TOKENS + s0] = t; wt_list[e0 * T_TOKENS + s0] = w0;
  int s1 = lbase[e1] + l1;
  tok_list[e1 * T_TOKENS + s1] = t; wt_list[e1 * T_TOKENS + s1] = w1;
  if (slots) {
    slots[2 * t]     = e0 * T_TOKENS + s0;
    slots[2 * t + 1] = e1 * T_TOKENS + s1;
  }
}

#define LD_W1(dst, base)                                        \
  _Pragma("unroll")                                             \
  for (int i = 0; i < 4; i++) {                                 \
    dst[i][0] = *(const bf16x8*)(w1b + (base + i) * 512);       \
    dst[i][1] = *(const bf16x8*)(w1b + (16 + base + i) * 512);  \
  }

#define MF_W1(src, base)                                                          \
  _Pragma("unroll")                                                               \
  for (int i = 0; i < 4; i++) {                                                   \
    int kci = base + i;                                                           \
    int xo = ((kci * 4 + g) ^ xsw) << 3;                                          \
    bf16x8 af0 = *(const bf16x8*)&Xs[xbase0 + xo];                                \
    bf16x8 af1 = *(const bf16x8*)&Xs[xbase0 + 16 * 512 + xo];                     \
    H00 = __builtin_amdgcn_mfma_f32_16x16x32_bf16(af0, src[i][0], H00, 0, 0, 0);  \
    H01 = __builtin_amdgcn_mfma_f32_16x16x32_bf16(af0, src[i][1], H01, 0, 0, 0);  \
    H10 = __builtin_amdgcn_mfma_f32_16x16x32_bf16(af1, src[i][0], H10, 0, 0, 0);  \
    H11 = __builtin_amdgcn_mfma_f32_16x16x32_bf16(af1, src[i][1], H11, 0, 0, 0);  \
  }

#define LD_W2(klbase)                                                             \
  _Pragma("unroll")                                                               \
  for (int kl = klbase; kl < klbase + 2; kl++) {                                  \
    const unsigned short* w2b =                                                   \
        W2p + ((long)((e * 64 + (fc >> 5) + kl) * 32 + wave * 4) * 64 + lane) * 8;\
    _Pragma("unroll")                                                             \
    for (int nt = 0; nt < 4; nt++)                                                \
      w2r[kl][nt] = *(const bf16x8*)(w2b + nt * 512);                             \
  }

// R6 == R5 with the nontemporal builtins fixed to use ext_vector f32x4
// (HIP's float4 is a class type the builtin rejects).
// R5 theory: keep R4's deep register pipeline but make it REAL by replacing
// the per-iter __syncthreads (which drains vmcnt(0), killing every
// cross-barrier prefetch -- the reason R2==R3==R4==~600us) with a raw
// s_barrier preceded only by lgkmcnt(0) (Hs ds_writes are the only
// cross-wave dependency). Weight loads now genuinely stay in flight across
// the barrier (T4). Plus T5 setprio around MFMA clusters, and nontemporal
// hints on the streaming paths so they don't evict L2-resident weights.
template <bool USE_PARTIAL>
__global__ __launch_bounds__(512, 2) void ffn_kernel(
    const float* __restrict__ x,
    const unsigned short* __restrict__ W1p,
    const unsigned short* __restrict__ W2p,
    const float* __restrict__ b1, const float* __restrict__ b2,
    const int* __restrict__ counts,
    const int* __restrict__ tok_list, const float* __restrict__ wt_list,
    float* __restrict__ partial,
    float* __restrict__ out) {
  __shared__ unsigned short Xs[64 * 512];   // 64 KB
  __shared__ unsigned short Hs[2][64 * 128];// 32 KB double-buffered

  const int e = blockIdx.x & 7;        // expert -> XCD pinning
  const int tile = blockIdx.x >> 3;
  const int cnt = counts[e];
  const int m0 = tile * 64;
  if (m0 >= cnt) return;
  const int rows = min(64, cnt - m0);

  // compact base row for this expert in the partial buffer
  int pbase = 0;
  if (USE_PARTIAL) {
    #pragma unroll
    for (int i = 0; i < NEXP; i++) pbase += (i < e) ? counts[i] : 0;
  }

  const int tid = threadIdx.x;
  const int wave = tid >> 6, lane = tid & 63;
  const int g = lane >> 4, ln = lane & 15;
  const int mw = wave >> 2, nw = wave & 3;   // GEMM1 wave grid: 2(m) x 4(n)

  // stage gathered X tile (fp32 -> bf16), XOR-swizzled; nontemporal reads
  #pragma unroll 4
  for (int c = tid; c < 64 * 128; c += 512) {
    int r = c >> 7, q = c & 127;
    ushort4 bv = {0, 0, 0, 0};
    if (r < rows) {
      int tk = tok_list[e * T_TOKENS + m0 + r];
      const f32x4 v = __builtin_nontemporal_load((const f32x4*)(x + (long)tk * DIM + q * 4));
      bv.x = f2bf(v[0]); bv.y = f2bf(v[1]); bv.z = f2bf(v[2]); bv.w = f2bf(v[3]);
    }
    int addr = r * 512 + ((((q >> 1) ^ (r & 7)) << 3) | ((q & 1) << 2));
    *(ushort4*)&Xs[addr] = bv;
  }
  LGKM_BARRIER();

  const f32x4 zero4 = {0.f, 0.f, 0.f, 0.f};
  f32x4 Yacc[4][4];
  #pragma unroll
  for (int a = 0; a < 4; a++)
    #pragma unroll
    for (int b = 0; b < 4; b++) Yacc[a][b] = zero4;

  const int xsw = ln & 7;
  const int xbase0 = (mw * 32 + ln) * 512;

  const unsigned short* const w1b_first =
      W1p + ((long)(e * 128 + nw * 2) * 16) * 512 + lane * 8;
  const unsigned short* w1b = w1b_first;

  bf16x8 wA[4][2], wB[4][2], wC[4][2], w2r[4][4];
  // prologue: prefetch iter-0 kci 0..7 (one full-latency wait per block, amortized)
  LD_W1(wA, 0);
  LD_W1(wB, 4);

  for (int fc = 0; fc < FDIM; fc += 128) {
    unsigned short* Hp = &Hs[(fc >> 7) & 1][0];
    f32x4 H00 = zero4, H01 = zero4, H10 = zero4, H11 = zero4;

    LD_W1(wC, 8);        // in-iter batch: kci 8..11
    __builtin_amdgcn_s_setprio(1);
    MF_W1(wA, 0);        // cross-iter prefetched -> wait fully covered
    MF_W1(wB, 4);        // cross-iter prefetched
    __builtin_amdgcn_s_setprio(0);
    LD_W1(wB, 12);       // wB free -> reload with kci 12..15
    __builtin_amdgcn_s_setprio(1);
    MF_W1(wC, 8);        // covered by MF(wA)+MF(wB)
    __builtin_amdgcn_s_setprio(0);
    LD_W2(0);            // GEMM2 kl 0,1 prefetch (now SURVIVES the barrier)
    // advance W1 base for next fc-iter (last iter: re-point at iter-0 data;
    // those prefetch loads are valid reads whose values are never used)
    w1b = (fc + 128 < FDIM) ? (w1b + 8 * 16 * 512) : w1b_first;
    LD_W1(wA, 0);        // next-iter kci 0..3 (cross-iter prefetch)
    __builtin_amdgcn_s_setprio(1);
    MF_W1(wB, 12);       // covered by MF(wC)+LD_W2+LD(wA_next)
    __builtin_amdgcn_s_setprio(0);
    LD_W1(wB, 4);        // next-iter kci 4..7 (cross-iter prefetch)

    // bias + relu -> Hs[p] (C-layout: col=lane&15, row=(lane>>4)*4+i)
    {
      float b1v0 = b1[e * FDIM + fc + nw * 32 + ln];
      float b1v1 = b1[e * FDIM + fc + nw * 32 + 16 + ln];
      #pragma unroll
      for (int mi = 0; mi < 2; mi++) {
        #pragma unroll
        for (int ni = 0; ni < 2; ni++) {
          const f32x4& hv = mi ? (ni ? H11 : H10) : (ni ? H01 : H00);
          float bv = ni ? b1v1 : b1v0;
          int fl = nw * 32 + ni * 16 + ln;
          #pragma unroll
          for (int i = 0; i < 4; i++) {
            int m = mw * 32 + mi * 16 + g * 4 + i;
            int addr = m * 128 + ((((fl >> 3) ^ (m & 7)) << 3) | (fl & 7));
            Hp[addr] = f2bf(fmaxf(hv[i] + bv, 0.f));
          }
        }
      }
    }
    // single NON-DRAINING barrier per fc-iter: weight prefetches stay in
    // flight; only Hs writes (lgkm) must be visible.
    LGKM_BARRIER();

    LD_W2(2);          // prefetch kl 2,3 under kl 0,1 MFMAs

    __builtin_amdgcn_s_setprio(1);
    #pragma unroll
    for (int kl = 0; kl < 4; kl++) {
      bf16x8 ha[4];
      #pragma unroll
      for (int mt = 0; mt < 4; mt++) {
        int m = mt * 16 + ln;
        ha[mt] = *(const bf16x8*)&Hp[m * 128 + ((((kl * 4 + g) ^ (m & 7)) << 3))];
      }
      #pragma unroll
      for (int nt = 0; nt < 4; nt++)
        #pragma unroll
        for (int mt = 0; mt < 4; mt++)
          Yacc[mt][nt] = __builtin_amdgcn_mfma_f32_16x16x32_bf16(ha[mt], w2r[kl][nt], Yacc[mt][nt], 0, 0, 0);
    }
    __builtin_amdgcn_s_setprio(0);
  }

  // epilogue: (Y + b2) * token_weight
  #pragma unroll
  for (int mt = 0; mt < 4; mt++) {
    #pragma unroll
    for (int i = 0; i < 4; i++) {
      int m = mt * 16 + g * 4 + i;
      if (m < rows) {
        float w = wt_list[e * T_TOKENS + m0 + m];
        if (USE_PARTIAL) {
          // coalesced non-atomic store of this assignment's weighted row slice
          float* dst = partial + ((long)(pbase + m0 + m)) * DIM;
          #pragma unroll
          for (int nt = 0; nt < 4; nt++) {
            int d = (wave * 4 + nt) * 16 + ln;
            __builtin_nontemporal_store((Yacc[mt][nt][i] + b2[e * DIM + d]) * w, dst + d);
          }
        } else {
          int tk = tok_list[e * T_TOKENS + m0 + m];
          #pragma unroll
          for (int nt = 0; nt < 4; nt++) {
            int d = (wave * 4 + nt) * 16 + ln;
            float v = (Yacc[mt][nt][i] + b2[e * DIM + d]) * w;
            atomicAdd(out + (long)tk * DIM + d, v);
          }
        }
      }
    }
  }
}

// out[t] = partial[row(slots[2t])] + partial[row(slots[2t+1])] ; pure
// streaming, no RMW. row(slot) = prefix[e] + s with slot = e*T_TOKENS + s.
// 256 threads = 2 tokens/block, float4 per thread.
__global__ __launch_bounds__(256) void combine_kernel(
    const float* __restrict__ partial, const int* __restrict__ slots,
    const int* __restrict__ counts, float* __restrict__ out) {
  __shared__ int pre[NEXP];
  if (threadIdx.x == 0) {
    int a = 0;
    #pragma unroll
    for (int i = 0; i < NEXP; i++) { pre[i] = a; a += counts[i]; }
  }
  __syncthreads();
  const int tid = threadIdx.x;
  const int tk = blockIdx.x * 2 + (tid >> 7);
  const int q = (tid & 127) << 2;
  const int2 sp = *(const int2*)(slots + 2 * tk);
  const long r0 = pre[sp.x >> 15] + (sp.x & (T_TOKENS - 1));
  const long r1 = pre[sp.y >> 15] + (sp.y & (T_TOKENS - 1));
  const f32x4 a = __builtin_nontemporal_load((const f32x4*)(partial + r0 * DIM + q));
  const f32x4 b = __builtin_nontemporal_load((const f32x4*)(partial + r1 * DIM + q));
  f32x4 r = a + b;
  __builtin_nontemporal_store(r, (f32x4*)(out + (long)tk * DIM + q));
}

extern "C" void kernel_launch(void* const* d_in, const int* in_sizes, int n_in,
                              void* d_out, int out_size, void* d_ws, size_t ws_size,
                              hipStream_t stream) {
  (void)in_sizes; (void)n_in; (void)out_size;
  const float* x  = (const float*)d_in[0];
  const float* Wr = (const float*)d_in[1];
  const float* br = (const float*)d_in[2];
  const float* W1 = (const float*)d_in[3];
  const float* b1 = (const float*)d_in[4];
  const float* W2 = (const float*)d_in[5];
  const float* b2 = (const float*)d_in[6];
  float* out = (float*)d_out;

  char* ws = (char*)d_ws;
  // layout (bytes):
  //   counts   @ 0          (1,024)
  //   tok_list @ 1,024      (1,048,576)
  //   wt_list  @ 1,049,600  (1,048,576)
  //   slots    @ 2,098,176  (262,144)
  //   W1p      @ 2,360,320  (16,777,216)
  //   W2p      @ 19,137,536 (16,777,216)
  //   partial  @ 35,914,752 (134,217,728 = 2*T rows x 512 f32) -> end 170,132,480
  int*            counts   = (int*)(ws);
  int*            tok_list = (int*)(ws + 1024);
  float*          wt_list  = (float*)(ws + 1049600);
  int*            slots    = (int*)(ws + 2098176);
  unsigned short* W1p      = (unsigned short*)(ws + 2360320);
  unsigned short* W2p      = (unsigned short*)(ws + 19137536);
  float*          partial  = (float*)(ws + 35914752);
  const size_t need_partial = 35914752ull + (size_t)T_TOKENS * 2 * DIM * sizeof(float);
  const bool use_partial = ws_size >= need_partial;

  hipMemsetAsync(counts, 0, 1024, stream);
  pack_w1_kernel<<<NEXP * 128, 256, 0, stream>>>(W1, W1p);
  pack_w2_kernel<<<NEXP * 32, 256, 0, stream>>>(W2, W2p);

  if (use_partial) {
    router_kernel<<<T_TOKENS / 256, 256, 0, stream>>>(x, Wr, br, counts, tok_list, wt_list, slots);
    ffn_kernel<true><<<T_TOKENS / 64 * NEXP, 512, 0, stream>>>(
        x, W1p, W2p, b1, b2, counts, tok_list, wt_list, partial, out);
    combine_kernel<<<T_TOKENS / 2, 256, 0, stream>>>(partial, slots, counts, out);
  } else {
    // fallback: original atomic-accumulate path
    hipMemsetAsync(out, 0, (size_t)T_TOKENS * DIM * sizeof(float), stream);
    router_kernel<<<T_TOKENS / 256, 256, 0, stream>>>(x, Wr, br, counts, tok_list, wt_list, nullptr);
    ffn_kernel<false><<<T_TOKENS / 64 * NEXP, 512, 0, stream>>>(
        x, W1p, W2p, b1, b2, counts, tok_list, wt_list, nullptr, out);
  }
}

// Round 7
// 619.010 us; speedup vs baseline: 1.3817x; 1.1400x over previous
//
#include <hip/hip_runtime.h>

#define T_TOKENS 32768
#define DIM 512
#define FDIM 2048
#define NEXP 8

typedef __attribute__((ext_vector_type(4))) float f32x4;
typedef __attribute__((ext_vector_type(8))) short bf16x8;

__device__ __forceinline__ unsigned short f2bf(float f) {
  unsigned int u = __float_as_uint(f);
  u += 0x7FFFu + ((u >> 16) & 1u);   // round-to-nearest-even
  return (unsigned short)(u >> 16);
}

// Barrier that does NOT drain vmcnt (R6, kept: -15%). hipcc's __syncthreads
// emits "s_waitcnt vmcnt(0) lgkmcnt(0); s_barrier" which kills in-flight
// register prefetches. Only LDS writes (lgkmcnt) need cross-wave visibility.
#define LGKM_BARRIER()                                        \
  do {                                                        \
    asm volatile("s_waitcnt lgkmcnt(0)" ::: "memory");        \
    __builtin_amdgcn_s_barrier();                             \
  } while (0)

// Pack W1 [E][D][F] fp32 -> fragment-linear bf16, line-coalesced reads via LDS.
// W1p[((e*128+ft)*16+kci)*512 + l*8 + j] = bf16(W1[e][kci*32+(l>>4)*8+j][ft*16+(l&15)])
__global__ void pack_w1_kernel(const float* __restrict__ W1, unsigned short* __restrict__ W1p) {
  __shared__ float L[512][17];
  const int b = blockIdx.x;          // e*128 + ft
  const int e = b >> 7, ft = b & 127;
  const int t = threadIdx.x;         // 256
  const int c = t & 15, r0 = t >> 4;
  const float* src = W1 + (long)e * 512 * 2048 + ft * 16 + c;
  #pragma unroll
  for (int ch = 0; ch < 32; ch++) {
    int r = ch * 16 + r0;
    L[r][c] = src[(long)r * 2048];
  }
  __syncthreads();
  #pragma unroll
  for (int s = 0; s < 4; s++) {
    int slot = s * 256 + t;
    int kci = slot >> 6, l = slot & 63;
    unsigned short tmp[8];
    #pragma unroll
    for (int j = 0; j < 8; j++)
      tmp[j] = f2bf(L[kci * 32 + (l >> 4) * 8 + j][l & 15]);
    *(ushort4*)(W1p + ((long)b * 16 + kci) * 512 + l * 8)     = *(ushort4*)&tmp[0];
    *(ushort4*)(W1p + ((long)b * 16 + kci) * 512 + l * 8 + 4) = *(ushort4*)&tmp[4];
  }
}

// Pack W2 [E][F][D] fp32 -> fragment-linear bf16, line-coalesced reads via LDS.
// W2p[((e*64+kc2i)*32+dt)*512 + l*8 + j] = bf16(W2[e][kc2i*32+(l>>4)*8+j][dt*16+(l&15)])
__global__ void pack_w2_kernel(const float* __restrict__ W2, unsigned short* __restrict__ W2p) {
  __shared__ float L[512][17];
  const int b = blockIdx.x;          // e*32 + dt
  const int e = b >> 5, dt = b & 31;
  const int t = threadIdx.x;
  const int c = t & 15, r0 = t >> 4;
  for (int ch = 0; ch < 4; ch++) {   // f in chunks of 512
    if (ch) __syncthreads();
    const float* src = W2 + ((long)e * 2048 + ch * 512) * 512 + dt * 16 + c;
    #pragma unroll
    for (int cc = 0; cc < 32; cc++) {
      int r = cc * 16 + r0;
      L[r][c] = src[(long)r * 512];
    }
    __syncthreads();
    #pragma unroll
    for (int s = 0; s < 4; s++) {
      int slot = s * 256 + t;
      int kciL = slot >> 6, l = slot & 63;
      unsigned short tmp[8];
      #pragma unroll
      for (int j = 0; j < 8; j++)
        tmp[j] = f2bf(L[kciL * 32 + (l >> 4) * 8 + j][l & 15]);
      long tt = (long)(e * 64 + ch * 16 + kciL) * 32 + dt;
      *(ushort4*)(W2p + tt * 512 + l * 8)     = *(ushort4*)&tmp[0];
      *(ushort4*)(W2p + tt * 512 + l * 8 + 4) = *(ushort4*)&tmp[4];
    }
  }
}

// one thread per token; per-block LDS histogram -> 8 global atomics per block.
__global__ void router_kernel(const float* __restrict__ x, const float* __restrict__ Wr,
                              const float* __restrict__ br, int* __restrict__ counts,
                              int* __restrict__ tok_list, float* __restrict__ wt_list,
                              int* __restrict__ slots) {
  __shared__ float WrS[NEXP][DIM];
  __shared__ int lcnt[NEXP];
  __shared__ int lbase[NEXP];
  const int tid = threadIdx.x;   // 256
  for (int i = tid; i < NEXP * DIM; i += 256) {
    int e = i >> 9, d = i & (DIM - 1);
    WrS[e][d] = Wr[d * NEXP + e];
  }
  if (tid < NEXP) lcnt[tid] = 0;
  __syncthreads();

  const int t = blockIdx.x * 256 + tid;
  const float* xr = x + (long)t * DIM;
  float acc[NEXP];
  #pragma unroll
  for (int e = 0; e < NEXP; e++) acc[e] = br[e];
  for (int d = 0; d < DIM; d += 4) {
    const float4 xv = *(const float4*)(xr + d);
    #pragma unroll
    for (int e = 0; e < NEXP; e++)
      acc[e] += xv.x * WrS[e][d] + xv.y * WrS[e][d + 1] +
                xv.z * WrS[e][d + 2] + xv.w * WrS[e][d + 3];
  }
  int e0 = 0; float v0 = acc[0];
  #pragma unroll
  for (int e = 1; e < NEXP; e++) if (acc[e] > v0) { v0 = acc[e]; e0 = e; }
  int e1 = -1; float v1 = -3.4e38f;
  #pragma unroll
  for (int e = 0; e < NEXP; e++) if (e != e0 && acc[e] > v1) { v1 = acc[e]; e1 = e; }
  float w0 = 1.f / (1.f + __expf(v1 - v0));
  float w1 = 1.f - w0;

  int l0 = atomicAdd(&lcnt[e0], 1);
  int l1 = atomicAdd(&lcnt[e1], 1);
  __syncthreads();
  if (tid < NEXP) lbase[tid] = atomicAdd(&counts[tid], lcnt[tid]);
  __syncthreads();
  int s0 = lbase[e0] + l0;
  tok_list[e0 * T_TOKENS + s0] = t; wt_list[e0 * T_TOKENS + s0] = w0;
  int s1 = lbase[e1] + l1;
  tok_list[e1 * T_TOKENS + s1] = t; wt_list[e1 * T_TOKENS + s1] = w1;
  if (slots) {
    slots[2 * t]     = e0 * T_TOKENS + s0;
    slots[2 * t + 1] = e1 * T_TOKENS + s1;
  }
}

// load 8 consecutive kci fragment-lines of this wave's ft column block
#define LD8(dst, ptr, kbase)                                    \
  _Pragma("unroll")                                             \
  for (int i = 0; i < 8; i++)                                   \
    dst[i] = *(const bf16x8*)((ptr) + (kbase + i) * 512);

// 8 kci x 4 m-tiles of MFMA; af re-read from Xs per (kci, mt)
#define MF8(src, kbase)                                                            \
  _Pragma("unroll")                                                                \
  for (int i = 0; i < 8; i++) {                                                    \
    int kci = (kbase) + i;                                                         \
    int xo = ((kci * 4 + g) ^ xsw) << 3;                                           \
    _Pragma("unroll")                                                              \
    for (int mt = 0; mt < 4; mt++) {                                               \
      bf16x8 af = *(const bf16x8*)&Xs[(mt * 16 + ln) * 512 + xo];                  \
      H[mt] = __builtin_amdgcn_mfma_f32_16x16x32_bf16(af, src[i], H[mt], 0, 0, 0); \
    }                                                                              \
  }

#define LD_W2(klbase)                                                             \
  _Pragma("unroll")                                                               \
  for (int kl = klbase; kl < klbase + 2; kl++) {                                  \
    const unsigned short* w2b =                                                   \
        W2p + ((long)((e * 64 + (fc >> 5) + kl) * 32 + wave * 4) * 64 + lane) * 8;\
    _Pragma("unroll")                                                             \
    for (int nt = 0; nt < 4; nt++)                                                \
      w2r[kl][nt] = *(const bf16x8*)(w2b + nt * 512);                             \
  }

// R7: GEMM1 wave grid 2m x 4n -> 1m x 8n. Evidence from R6: VGPR_Count=128
// (launch_bounds permits 256) proves the compiler sank the R4/R6 3-buffer
// prefetch (needs ~240 live regs); and the 2x4 grid loads every W1 fragment
// TWICE per block (mw pair duplication). New grid: each wave owns all 64 m
// x 16 f-cols (one ft): W1 loads/wave/iter 32 -> 16, zero duplication, and
// the 2-batch ping-pong live set (wA+wB 64 + w2r 64 + Yacc 64 + H 16 ~ 238)
// fits 256 VGPR so the prefetch can actually survive register allocation.
// Each load batch is covered by >=600 issued cycles (32 MFMAs or
// GEMM2+barrier). Cost: GEMM1 Xs ds_reads 32 -> 64/wave/iter (conflict-free
// 2-way). Hs layout, GEMM2, epilogue unchanged. Keep LGKM_BARRIER + setprio
// + nontemporal streaming hints.
template <bool USE_PARTIAL>
__global__ __launch_bounds__(512, 2) void ffn_kernel(
    const float* __restrict__ x,
    const unsigned short* __restrict__ W1p,
    const unsigned short* __restrict__ W2p,
    const float* __restrict__ b1, const float* __restrict__ b2,
    const int* __restrict__ counts,
    const int* __restrict__ tok_list, const float* __restrict__ wt_list,
    float* __restrict__ partial,
    float* __restrict__ out) {
  __shared__ unsigned short Xs[64 * 512];   // 64 KB
  __shared__ unsigned short Hs[2][64 * 128];// 32 KB double-buffered

  const int e = blockIdx.x & 7;        // expert -> XCD pinning
  const int tile = blockIdx.x >> 3;
  const int cnt = counts[e];
  const int m0 = tile * 64;
  if (m0 >= cnt) return;
  const int rows = min(64, cnt - m0);

  // compact base row for this expert in the partial buffer
  int pbase = 0;
  if (USE_PARTIAL) {
    #pragma unroll
    for (int i = 0; i < NEXP; i++) pbase += (i < e) ? counts[i] : 0;
  }

  const int tid = threadIdx.x;
  const int wave = tid >> 6, lane = tid & 63;
  const int g = lane >> 4, ln = lane & 15;

  // stage gathered X tile (fp32 -> bf16), XOR-swizzled; nontemporal reads
  #pragma unroll 4
  for (int c = tid; c < 64 * 128; c += 512) {
    int r = c >> 7, q = c & 127;
    ushort4 bv = {0, 0, 0, 0};
    if (r < rows) {
      int tk = tok_list[e * T_TOKENS + m0 + r];
      const f32x4 v = __builtin_nontemporal_load((const f32x4*)(x + (long)tk * DIM + q * 4));
      bv.x = f2bf(v[0]); bv.y = f2bf(v[1]); bv.z = f2bf(v[2]); bv.w = f2bf(v[3]);
    }
    int addr = r * 512 + ((((q >> 1) ^ (r & 7)) << 3) | ((q & 1) << 2));
    *(ushort4*)&Xs[addr] = bv;
  }
  LGKM_BARRIER();

  const f32x4 zero4 = {0.f, 0.f, 0.f, 0.f};
  f32x4 Yacc[4][4];
  #pragma unroll
  for (int a = 0; a < 4; a++)
    #pragma unroll
    for (int b = 0; b < 4; b++) Yacc[a][b] = zero4;

  const int xsw = ln & 7;

  // this wave's W1 column block: ft = fc/16 + wave (8 waves cover 8 ft/iter)
  const unsigned short* const w1b_first =
      W1p + ((long)(e * 128 + wave) * 16) * 512 + lane * 8;
  const unsigned short* w1b = w1b_first;

  bf16x8 wA[8], wB[8], w2r[4][4];
  // prologue: prefetch iter-0 kci 0..7 (one exposed wait per block)
  LD8(wA, w1b, 0);

  for (int fc = 0; fc < FDIM; fc += 128) {
    unsigned short* Hp = &Hs[(fc >> 7) & 1][0];
    f32x4 H[4];
    #pragma unroll
    for (int mt = 0; mt < 4; mt++) H[mt] = zero4;

    LD8(wB, w1b, 8);     // this iter kci 8..15, covered by MF8(wA)
    __builtin_amdgcn_s_setprio(1);
    MF8(wA, 0);          // prefetched last iter -> wait covered
    __builtin_amdgcn_s_setprio(0);
    LD_W2(0);            // GEMM2 kl 0,1 prefetch (survives barrier)
    __builtin_amdgcn_s_setprio(1);
    MF8(wB, 8);          // covered by MF8(wA) ~620 issued cycles
    __builtin_amdgcn_s_setprio(0);
    // next-iter W1 base (last iter: re-point at iter-0 lines; the prefetch
    // reads are valid but their values are never consumed)
    w1b = (fc + 128 < FDIM) ? (w1b + 8 * 16 * 512) : w1b_first;
    LD8(wA, w1b, 0);     // next-iter kci 0..7; waited next iter after
                         // Hs-write + barrier + GEMM2 (>=1500 cycles cover)

    // bias + relu -> Hs[p] (C-layout: col fl = wave*16+ln, row mt*16+g*4+i)
    {
      float b1v = b1[e * FDIM + fc + wave * 16 + ln];
      int fl = wave * 16 + ln;
      #pragma unroll
      for (int mt = 0; mt < 4; mt++) {
        #pragma unroll
        for (int i = 0; i < 4; i++) {
          int m = mt * 16 + g * 4 + i;
          int addr = m * 128 + ((((fl >> 3) ^ (m & 7)) << 3) | (fl & 7));
          Hp[addr] = f2bf(fmaxf(H[mt][i] + b1v, 0.f));
        }
      }
    }
    // single NON-DRAINING barrier per fc-iter (Hs double-buffered):
    // weight prefetches stay in flight; only Hs writes must be visible.
    LGKM_BARRIER();

    LD_W2(2);          // prefetch kl 2,3 under kl 0,1 MFMAs

    __builtin_amdgcn_s_setprio(1);
    #pragma unroll
    for (int kl = 0; kl < 4; kl++) {
      bf16x8 ha[4];
      #pragma unroll
      for (int mt = 0; mt < 4; mt++) {
        int m = mt * 16 + ln;
        ha[mt] = *(const bf16x8*)&Hp[m * 128 + ((((kl * 4 + g) ^ (m & 7)) << 3))];
      }
      #pragma unroll
      for (int nt = 0; nt < 4; nt++)
        #pragma unroll
        for (int mt = 0; mt < 4; mt++)
          Yacc[mt][nt] = __builtin_amdgcn_mfma_f32_16x16x32_bf16(ha[mt], w2r[kl][nt], Yacc[mt][nt], 0, 0, 0);
    }
    __builtin_amdgcn_s_setprio(0);
  }

  // epilogue: (Y + b2) * token_weight
  #pragma unroll
  for (int mt = 0; mt < 4; mt++) {
    #pragma unroll
    for (int i = 0; i < 4; i++) {
      int m = mt * 16 + g * 4 + i;
      if (m < rows) {
        float w = wt_list[e * T_TOKENS + m0 + m];
        if (USE_PARTIAL) {
          // coalesced non-atomic store of this assignment's weighted row slice
          float* dst = partial + ((long)(pbase + m0 + m)) * DIM;
          #pragma unroll
          for (int nt = 0; nt < 4; nt++) {
            int d = (wave * 4 + nt) * 16 + ln;
            __builtin_nontemporal_store((Yacc[mt][nt][i] + b2[e * DIM + d]) * w, dst + d);
          }
        } else {
          int tk = tok_list[e * T_TOKENS + m0 + m];
          #pragma unroll
          for (int nt = 0; nt < 4; nt++) {
            int d = (wave * 4 + nt) * 16 + ln;
            float v = (Yacc[mt][nt][i] + b2[e * DIM + d]) * w;
            atomicAdd(out + (long)tk * DIM + d, v);
          }
        }
      }
    }
  }
}

// out[t] = partial[row(slots[2t])] + partial[row(slots[2t+1])] ; pure
// streaming, no RMW. row(slot) = prefix[e] + s with slot = e*T_TOKENS + s.
__global__ __launch_bounds__(256) void combine_kernel(
    const float* __restrict__ partial, const int* __restrict__ slots,
    const int* __restrict__ counts, float* __restrict__ out) {
  __shared__ int pre[NEXP];
  if (threadIdx.x == 0) {
    int a = 0;
    #pragma unroll
    for (int i = 0; i < NEXP; i++) { pre[i] = a; a += counts[i]; }
  }
  __syncthreads();
  const int tid = threadIdx.x;
  const int tk = blockIdx.x * 2 + (tid >> 7);
  const int q = (tid & 127) << 2;
  const int2 sp = *(const int2*)(slots + 2 * tk);
  const long r0 = pre[sp.x >> 15] + (sp.x & (T_TOKENS - 1));
  const long r1 = pre[sp.y >> 15] + (sp.y & (T_TOKENS - 1));
  const f32x4 a = __builtin_nontemporal_load((const f32x4*)(partial + r0 * DIM + q));
  const f32x4 b = __builtin_nontemporal_load((const f32x4*)(partial + r1 * DIM + q));
  f32x4 r = a + b;
  __builtin_nontemporal_store(r, (f32x4*)(out + (long)tk * DIM + q));
}

extern "C" void kernel_launch(void* const* d_in, const int* in_sizes, int n_in,
                              void* d_out, int out_size, void* d_ws, size_t ws_size,
                              hipStream_t stream) {
  (void)in_sizes; (void)n_in; (void)out_size;
  const float* x  = (const float*)d_in[0];
  const float* Wr = (const float*)d_in[1];
  const float* br = (const float*)d_in[2];
  const float* W1 = (const float*)d_in[3];
  const float* b1 = (const float*)d_in[4];
  const float* W2 = (const float*)d_in[5];
  const float* b2 = (const float*)d_in[6];
  float* out = (float*)d_out;

  char* ws = (char*)d_ws;
  // layout (bytes):
  //   counts   @ 0          (1,024)
  //   tok_list @ 1,024      (1,048,576)
  //   wt_list  @ 1,049,600  (1,048,576)
  //   slots    @ 2,098,176  (262,144)
  //   W1p      @ 2,360,320  (16,777,216)
  //   W2p      @ 19,137,536 (16,777,216)
  //   partial  @ 35,914,752 (134,217,728 = 2*T rows x 512 f32) -> end 170,132,480
  int*            counts   = (int*)(ws);
  int*            tok_list = (int*)(ws + 1024);
  float*          wt_list  = (float*)(ws + 1049600);
  int*            slots    = (int*)(ws + 2098176);
  unsigned short* W1p      = (unsigned short*)(ws + 2360320);
  unsigned short* W2p      = (unsigned short*)(ws + 19137536);
  float*          partial  = (float*)(ws + 35914752);
  const size_t need_partial = 35914752ull + (size_t)T_TOKENS * 2 * DIM * sizeof(float);
  const bool use_partial = ws_size >= need_partial;

  hipMemsetAsync(counts, 0, 1024, stream);
  pack_w1_kernel<<<NEXP * 128, 256, 0, stream>>>(W1, W1p);
  pack_w2_kernel<<<NEXP * 32, 256, 0, stream>>>(W2, W2p);

  if (use_partial) {
    router_kernel<<<T_TOKENS / 256, 256, 0, stream>>>(x, Wr, br, counts, tok_list, wt_list, slots);
    ffn_kernel<true><<<T_TOKENS / 64 * NEXP, 512, 0, stream>>>(
        x, W1p, W2p, b1, b2, counts, tok_list, wt_list, partial, out);
    combine_kernel<<<T_TOKENS / 2, 256, 0, stream>>>(partial, slots, counts, out);
  } else {
    // fallback: original atomic-accumulate path
    hipMemsetAsync(out, 0, (size_t)T_TOKENS * DIM * sizeof(float), stream);
    router_kernel<<<T_TOKENS / 256, 256, 0, stream>>>(x, Wr, br, counts, tok_list, wt_list, nullptr);
    ffn_kernel<false><<<T_TOKENS / 64 * NEXP, 512, 0, stream>>>(
        x, W1p, W2p, b1, b2, counts, tok_list, wt_list, nullptr, out);
  }
}